// Round 7
// baseline (8516.079 us; speedup 1.0000x reference)
//
#include <hip/hip_runtime.h>
#include <stdint.h>

// R11: z-PARTIAL exchange (from R10's 5991 us). R10 ledger: step=14.0k cy,
// busy 4.4k, stall ~9.6k — dominated by 3 serial UC round trips (poll is a
// full RT even on hit; phf data RT; publish-ack drain), because h is made at
// step-END and needed at step-START (zero slack). R11 moves the dependent
// compute to the producer: each WG computes P = W_hh[own K-rows, partner
// cols] . h_own EARLY in the step (h_own known at top), publishes f32
// partials in MFMA C-layout (zero repack), consumes partner partials LATE
// (at gate time): z = acc(own+x) + P_recv + b. ~full-step slack hides all
// fabric latency. Same MFMA count (K=128xN=1024 == K=256xN=512). y via
// own-slice y-partials (phf + extraction deleted). Per-wave flags, relaxed
// system-scope; publish precedes any cross-WG wait => no deadlock; parity
// overwrite safety by flag-chain induction. ws ~8.7MB.

#define B_TOTAL   1024
#define H_DIM     256
#define F_WARM    32
#define F_AUTO    24
#define O_DIM     8
#define T_WARM    512
#define T_TOTAL   1024
#define N4H       1024
#define A_STR     168   // x(32)+h(128)+pad(8): 336 B/row, 16B-aligned

typedef __attribute__((ext_vector_type(8))) short short8;
typedef __attribute__((ext_vector_type(4))) float float4v;

#define GLOBAL_AS __attribute__((address_space(1)))
#define LDS_AS    __attribute__((address_space(3)))

__device__ __forceinline__ short f2bf(float x) {
    union { float f; uint32_t u; } v; v.f = x;
    uint32_t r = v.u + 0x7FFFu + ((v.u >> 16) & 1u);   // RNE
    return (short)(r >> 16);
}
__device__ __forceinline__ float sigmoid_(float x) {
    const float e = __expf(-x);
    return __builtin_amdgcn_rcpf(1.0f + e);
}
__device__ __forceinline__ float tanh_(float x) {
    const float e = __expf(-2.0f * fabsf(x));
    const float t = (1.0f - e) * __builtin_amdgcn_rcpf(1.0f + e);
    return x >= 0.0f ? t : -t;
}
__device__ __forceinline__ void uc_store_f(float v, float* p) {
    union { float f; uint32_t u; } x; x.f = v;
    __hip_atomic_store((uint32_t*)p, x.u, __ATOMIC_RELAXED,
                       __HIP_MEMORY_SCOPE_SYSTEM);
}
__device__ __forceinline__ float uc_load_f(const float* p) {
    union { uint32_t u; float f; } x;
    x.u = __hip_atomic_load((const uint32_t*)p, __ATOMIC_RELAXED,
                            __HIP_MEMORY_SCOPE_SYSTEM);
    return x.f;
}

__global__ __launch_bounds__(256, 1)
void lstm_zp(const float* __restrict__ c0, const float* __restrict__ h0,
             const float* __restrict__ warm, const float* __restrict__ autoin,
             const float* __restrict__ W_ih, const float* __restrict__ W_hh,
             const float* __restrict__ bvec, const float* __restrict__ W_out,
             const float* __restrict__ b_out, float* __restrict__ out,
             unsigned short* __restrict__ wsp)
{
    const int tid  = threadIdx.x;
    const int w    = tid >> 6;        // wave 0..3 -> own h-units [w*32, +32)
    const int l    = tid & 63;
    const int n16  = l & 15;          // MFMA n / A row (m)
    const int kg   = l >> 4;          // k-group 0..3
    const int bid  = blockIdx.x;
    const int half = bid >> 6;        // N-half: h-units [half*128, +128)
    const int row0 = (bid & 63) * 16; // batch rows
    const int hb   = half * 128;      // own h base (global h index)
    const int qb   = 128 - hb;        // partner h base

    // ws layout: flags [0,32KB) (bid*4+w)*64; ybuf [32KB,288KB) 1KB/(bid,par);
    //            zbuf [288KB,+8MB) 1KB/tile, tile=((bid*2+par)*32 + w*8 + g*2+j)
    uint32_t* flg_my = (uint32_t*)((char*)wsp + ((size_t)bid * 4 + w) * 64);
    uint32_t* flg_pt = (uint32_t*)((char*)wsp + ((size_t)(bid ^ 64) * 4 + w) * 64);
    char* ybase = (char*)wsp + 32768;
    char* zbase = (char*)wsp + 294912;

    __shared__ __align__(16) short Abuf[2][16 * A_STR]; // ping-pong A tiles
    __shared__ __align__(16) unsigned short wsWl[4096]; // W_out MFMA B-frags
    __shared__ float biasL[512];                        // own 4 gates x 128
    __shared__ __align__(16) float xstage[512];         // x_{t+1} prefetch

    // ---- W_out frags -> LDS ----
    for (int idx = tid; idx < 4096; idx += 256) {
        const int i = idx & 7, lane = (idx >> 3) & 63, kk = idx >> 9;
        const int k = kk * 32 + (lane >> 4) * 8 + i;
        const int n = lane & 15;
        wsWl[idx] = (unsigned short)((n < O_DIM) ? f2bf(W_out[k * O_DIM + n]) : (short)0);
    }
    // ---- bias: own 512 cols, layout [g][128] ----
    #pragma unroll
    for (int e = 0; e < 2; ++e) {
        const int idx = tid + e * 256;
        const int g = idx >> 7, loc = idx & 127;
        biasL[idx] = bvec[g * 256 + hb + loc];
    }

    // ---- register weights: 72 frags (compile-time indexed) ----
    short8 bwx[4][2];       // x chunk: W_ih rows 0..31, OWN cols
    short8 bwo[4][4][2];    // own K-rows (hb+), OWN cols
    short8 bwq[4][4][2];    // own K-rows (hb+), PARTNER cols
    #pragma unroll
    for (int g = 0; g < 4; ++g)
        #pragma unroll
        for (int j = 0; j < 2; ++j) {
            const int col  = g * 256 + hb + w * 32 + j * 16 + n16;
            const int qcol = g * 256 + qb + w * 32 + j * 16 + n16;
            {
                short8 f;
                #pragma unroll
                for (int i = 0; i < 8; ++i)
                    f[i] = f2bf(W_ih[(kg * 8 + i) * N4H + col]);
                bwx[g][j] = f;
            }
            #pragma unroll
            for (int c = 0; c < 4; ++c) {
                short8 f, q;
                #pragma unroll
                for (int i = 0; i < 8; ++i) {
                    const int kr = hb + c * 32 + kg * 8 + i;   // OWN K rows
                    f[i] = f2bf(W_hh[kr * N4H + col]);
                    q[i] = f2bf(W_hh[kr * N4H + qcol]);
                }
                bwo[c][g][j] = f;
                bwq[c][g][j] = q;
            }
        }

    const float bout = (w == 0 && n16 < O_DIM) ? b_out[n16] : 0.0f;

    // ---- c state ----
    float creg[2][4];
    #pragma unroll
    for (int j = 0; j < 2; ++j)
        #pragma unroll
        for (int r = 0; r < 4; ++r)
            creg[j][r] = c0[(size_t)(row0 + kg * 4 + r) * H_DIM
                            + (hb + w * 32 + j * 16 + n16)];

    // ---- initial A (buf 0): x_0 + own h0 ----
    #pragma unroll
    for (int e = 0; e < 2; ++e) {
        const int idx = tid + e * 256;
        const int r = idx >> 5, cx = idx & 31;
        Abuf[0][r * A_STR + cx] =
            f2bf(warm[(size_t)(row0 + r) * (T_WARM * F_WARM) + cx]);   // t=0
    }
    #pragma unroll
    for (int e = 0; e < 8; ++e) {
        const int idx = tid + e * 256;
        const int r = idx >> 7, c = idx & 127;
        Abuf[0][r * A_STR + F_WARM + c] = f2bf(h0[(size_t)(row0 + r) * H_DIM + hb + c]);
    }

    __syncthreads();                            // prologue LDS published
    float bb[2][4];
    #pragma unroll
    for (int j = 0; j < 2; ++j)
        #pragma unroll
        for (int g = 0; g < 4; ++g)
            bb[j][g] = biasL[g * 128 + w * 32 + j * 16 + n16];

    const int aoff = n16 * A_STR + kg * 8;
    short* curp = &Abuf[0][0];
    short* nxtp = &Abuf[1][0];
    const short8* wsW8 = (const short8*)wsWl;

    for (int t = 0; t < T_TOTAL; ++t) {
        __syncthreads();                        // A: curp(h_{t-1}, x_t) ready

        const int par = t & 1;
        float* zmy = (float*)(zbase + ((((size_t)bid * 2 + par) * 32) + w * 8) * 1024);
        const float* zpt = (const float*)(zbase + ((((size_t)(bid ^ 64) * 2 + par) * 32) + w * 8) * 1024);
        float* ymy = (float*)(ybase + ((size_t)bid * 2 + par) * 1024);
        const float* ypt = (const float*)(ybase + ((size_t)(bid ^ 64) * 2 + par) * 1024);

        // ---- own A-frags (h_{t-1} own slice) ----
        const short* ab = curp + aoff;
        short8 afh[4];
        #pragma unroll
        for (int c = 0; c < 4; ++c)
            afh[c] = *(const short8*)(ab + 32 + c * 32);

        // ---- partner partials: P = W_hh[own rows, partner cols] . h_own ----
        float4v pacc[4][2];
        #pragma unroll
        for (int g = 0; g < 4; ++g)
            #pragma unroll
            for (int j = 0; j < 2; ++j)
                pacc[g][j] = (float4v){0.f, 0.f, 0.f, 0.f};
        #pragma unroll
        for (int c = 0; c < 4; ++c)
            #pragma unroll
            for (int g = 0; g < 4; ++g)
                #pragma unroll
                for (int j = 0; j < 2; ++j)
                    pacc[g][j] = __builtin_amdgcn_mfma_f32_16x16x32_bf16(
                                     afh[c], bwq[c][g][j], pacc[g][j], 0, 0, 0);

        // ---- wave0: own-slice y_{t-1} partial (no bias) ----
        float4v ya = (float4v){0.f, 0.f, 0.f, 0.f};
        if (w == 0) {
            #pragma unroll
            for (int c = 0; c < 4; ++c)
                ya = __builtin_amdgcn_mfma_f32_16x16x32_bf16(
                         afh[c], wsW8[(hb / 32 + c) * 64 + l], ya, 0, 0, 0);
        }

        // ---- publish partials (UC relaxed; C-layout, zero repack) ----
        #pragma unroll
        for (int g = 0; g < 4; ++g)
            #pragma unroll
            for (int j = 0; j < 2; ++j)
                #pragma unroll
                for (int rr = 0; rr < 4; ++rr)
                    uc_store_f(pacc[g][j][rr], &zmy[(g * 2 + j) * 256 + l * 4 + rr]);
        if (w == 0) {
            #pragma unroll
            for (int rr = 0; rr < 4; ++rr)
                uc_store_f(ya[rr], &ymy[l * 4 + rr]);
        }

        // ---- own partials (cover the store drain) ----
        float4v acc[4][2];
        #pragma unroll
        for (int g = 0; g < 4; ++g)
            #pragma unroll
            for (int j = 0; j < 2; ++j)
                acc[g][j] = (float4v){0.f, 0.f, 0.f, 0.f};
        #pragma unroll
        for (int c = 0; c < 4; ++c)
            #pragma unroll
            for (int g = 0; g < 4; ++g)
                #pragma unroll
                for (int j = 0; j < 2; ++j)
                    acc[g][j] = __builtin_amdgcn_mfma_f32_16x16x32_bf16(
                                    afh[c], bwo[c][g][j], acc[g][j], 0, 0, 0);

        // ---- drain publishes, release per-wave flag ----
        asm volatile("s_waitcnt vmcnt(0)" ::: "memory");
        if (l == 0)
            __hip_atomic_store(flg_my, (uint32_t)(t + 1),
                               __ATOMIC_RELAXED, __HIP_MEMORY_SCOPE_SYSTEM);

        // ---- async prefetch x_{t+1} -> xstage (consumed at step end) ----
        const int tn = t + 1;
        if (tn < T_TOTAL) {
            #pragma unroll
            for (int e = 0; e < 2; ++e) {
                const int idx = tid + e * 256;
                const int r = idx >> 5, cx = idx & 31;
                const float* gp;
                if (tn < T_WARM)
                    gp = &warm[(size_t)(row0 + r) * (T_WARM * F_WARM)
                               + (size_t)tn * F_WARM + cx];
                else
                    gp = &autoin[(size_t)(row0 + r) * (T_WARM * F_AUTO)
                                 + (size_t)(tn - T_WARM) * F_AUTO
                                 + ((cx < F_AUTO) ? cx : 0)];
                __builtin_amdgcn_global_load_lds(
                    (const GLOBAL_AS void*)gp,
                    (LDS_AS void*)&xstage[e * 256 + w * 64], 4, 0, 0);
            }
        }

        // ---- confirm partner wave-flag, then issue y/P loads (early) ----
        while (__hip_atomic_load(flg_pt, __ATOMIC_RELAXED,
                                 __HIP_MEMORY_SCOPE_SYSTEM) < (uint32_t)(t + 1))
            __builtin_amdgcn_s_sleep(1);
        asm volatile("" ::: "memory");

        float yr0 = 0.f, yr1 = 0.f, yr2 = 0.f, yr3 = 0.f;
        const int docomb = (w == 0 && t >= 1 && (half == 0 || t >= T_WARM));
        if (docomb) {
            yr0 = uc_load_f(&ypt[l * 4 + 0]);
            yr1 = uc_load_f(&ypt[l * 4 + 1]);
            yr2 = uc_load_f(&ypt[l * 4 + 2]);
            yr3 = uc_load_f(&ypt[l * 4 + 3]);
        }
        float pr[4][2][4];
        #pragma unroll
        for (int g = 0; g < 4; ++g)
            #pragma unroll
            for (int j = 0; j < 2; ++j)
                #pragma unroll
                for (int rr = 0; rr < 4; ++rr)
                    pr[g][j][rr] = uc_load_f(&zpt[(g * 2 + j) * 256 + l * 4 + rr]);

        // ---- wave0: y combine -> out + feedback cols ----
        if (docomb) {
            if (n16 < O_DIM) {
                float comb[4];
                comb[0] = ya[0] + yr0 + bout;
                comb[1] = ya[1] + yr1 + bout;
                comb[2] = ya[2] + yr2 + bout;
                comb[3] = ya[3] + yr3 + bout;
                if (half == 0) {
                    #pragma unroll
                    for (int r = 0; r < 4; ++r)
                        out[(size_t)(row0 + kg * 4 + r) * (T_TOTAL * O_DIM)
                            + (size_t)(t - 1) * O_DIM + n16] = comb[r];
                }
                if (t >= T_WARM) {                      // feedback cols [24,32)
                    #pragma unroll
                    for (int r = 0; r < 4; ++r)
                        curp[(kg * 4 + r) * A_STR + F_AUTO + n16] = f2bf(comb[r]);
                }
            }
        }

        if (t >= T_WARM) __syncthreads();       // B: feedback cols ready

        {
            const short8 af = *(const short8*)(ab);     // x chunk (+feedback)
            #pragma unroll
            for (int g = 0; g < 4; ++g)
                #pragma unroll
                for (int j = 0; j < 2; ++j)
                    acc[g][j] = __builtin_amdgcn_mfma_f32_16x16x32_bf16(
                                    af, bwx[g][j], acc[g][j], 0, 0, 0);
        }

        // ---- gates: z = acc(own+x) + P_recv + b ----
        uint32_t hp[4];
        #pragma unroll
        for (int j = 0; j < 2; ++j) {
            float hv0, hv1, hv2, hv3;
            #pragma unroll
            for (int r = 0; r < 4; ++r) {
                const float ig = sigmoid_(acc[0][j][r] + pr[0][j][r] + bb[j][0]);
                const float fg = sigmoid_(acc[1][j][r] + pr[1][j][r] + bb[j][1]);
                const float gg = tanh_(acc[2][j][r] + pr[2][j][r] + bb[j][2]);
                const float og = sigmoid_(acc[3][j][r] + pr[3][j][r] + bb[j][3]);
                const float cc = fg * creg[j][r] + ig * gg;
                creg[j][r] = cc;
                const float hh = og * tanh_(cc);
                if (r == 0) hv0 = hh; else if (r == 1) hv1 = hh;
                else if (r == 2) hv2 = hh; else hv3 = hh;
            }
            uint32_t u0, u1;
            asm("v_cvt_pk_bf16_f32 %0, %1, %2" : "=v"(u0) : "v"(hv0), "v"(hv1));
            asm("v_cvt_pk_bf16_f32 %0, %1, %2" : "=v"(u1) : "v"(hv2), "v"(hv3));
            hp[j * 2 + 0] = u0;
            hp[j * 2 + 1] = u1;
        }

        // ---- drain x-prefetch (long complete), commit x_{t+1} -> nxtp ----
        asm volatile("s_waitcnt vmcnt(0)" ::: "memory");
        if (tn < T_TOTAL) {
            #pragma unroll
            for (int e = 0; e < 2; ++e) {
                const int idx = tid + e * 256;
                const int r = idx >> 5, cx = idx & 31;
                if (tn < T_WARM || cx < F_AUTO)
                    nxtp[r * A_STR + cx] = f2bf(xstage[idx]);
            }
        }

        // ---- write own h_t into NEXT buffer ----
        #pragma unroll
        for (int j = 0; j < 2; ++j) {
            const int ac = F_WARM + w * 32 + j * 16 + n16;
            const uint32_t u0 = hp[j * 2], u1 = hp[j * 2 + 1];
            nxtp[(kg * 4 + 0) * A_STR + ac] = (short)(u0 & 0xFFFF);
            nxtp[(kg * 4 + 1) * A_STR + ac] = (short)(u0 >> 16);
            nxtp[(kg * 4 + 2) * A_STR + ac] = (short)(u1 & 0xFFFF);
            nxtp[(kg * 4 + 3) * A_STR + ac] = (short)(u1 >> 16);
        }

        { short* tswap = curp; curp = nxtp; nxtp = tswap; }
        // loop-top barrier publishes nxt buffer (h_t + x_{t+1})
    }

    // ---- epilogue: y_{T-1} from final h (wave0, via y-partials) ----
    __syncthreads();
    {
        const int par = T_TOTAL & 1;            // 0: last used at t=1022, safe
        float* ymy = (float*)(ybase + ((size_t)bid * 2 + par) * 1024);
        const float* ypt = (const float*)(ybase + ((size_t)(bid ^ 64) * 2 + par) * 1024);
        if (w == 0) {
            const short* ab = curp + aoff;
            float4v ya = (float4v){0.f, 0.f, 0.f, 0.f};
            #pragma unroll
            for (int c = 0; c < 4; ++c)
                ya = __builtin_amdgcn_mfma_f32_16x16x32_bf16(
                         *(const short8*)(ab + 32 + c * 32),
                         wsW8[(hb / 32 + c) * 64 + l], ya, 0, 0, 0);
            #pragma unroll
            for (int rr = 0; rr < 4; ++rr)
                uc_store_f(ya[rr], &ymy[l * 4 + rr]);
            asm volatile("s_waitcnt vmcnt(0)" ::: "memory");
            if (l == 0)
                __hip_atomic_store(flg_my, (uint32_t)(T_TOTAL + 1),
                                   __ATOMIC_RELAXED, __HIP_MEMORY_SCOPE_SYSTEM);
            while (__hip_atomic_load(flg_pt, __ATOMIC_RELAXED,
                                     __HIP_MEMORY_SCOPE_SYSTEM) < (uint32_t)(T_TOTAL + 1))
                __builtin_amdgcn_s_sleep(1);
            asm volatile("" ::: "memory");
            if (half == 0 && n16 < O_DIM) {
                #pragma unroll
                for (int r = 0; r < 4; ++r) {
                    const float yv = ya[r] + uc_load_f(&ypt[l * 4 + r]) + bout;
                    out[(size_t)(row0 + kg * 4 + r) * (T_TOTAL * O_DIM)
                        + (size_t)(T_TOTAL - 1) * O_DIM + n16] = yv;
                }
            }
        }
    }
}

extern "C" void kernel_launch(void* const* d_in, const int* in_sizes, int n_in,
                              void* d_out, int out_size, void* d_ws, size_t ws_size,
                              hipStream_t stream) {
    (void)in_sizes; (void)n_in; (void)out_size; (void)ws_size;
    const float* c0   = (const float*)d_in[0];
    const float* h0   = (const float*)d_in[1];
    const float* warm = (const float*)d_in[2];
    const float* aut  = (const float*)d_in[3];
    const float* Wih  = (const float*)d_in[4];
    const float* Whh  = (const float*)d_in[5];
    const float* b    = (const float*)d_in[6];
    const float* Wout = (const float*)d_in[7];
    const float* bout = (const float*)d_in[8];
    float* out = (float*)d_out;
    unsigned short* wsp = (unsigned short*)d_ws;
    // ws layout: [0,32KB) per-wave flags; [32KB,288KB) y-partials;
    //            [288KB, 288KB+8MB) z-partials (f32, MFMA C-layout).
    hipMemsetAsync(d_ws, 0, 32768, stream);
    hipLaunchKernelGGL(lstm_zp, dim3(128), dim3(256), 0, stream,
                       c0, h0, warm, aut, Wih, Whh, b, Wout, bout, out, wsp);
}

// Round 8
// 5991.154 us; speedup vs baseline: 1.4214x; 1.4214x over previous
//
#include <hip/hip_runtime.h>
#include <stdint.h>

// R12: R10 with exchange scope SYSTEM -> AGENT (R10: 5991 us best; R11's
// z-partial exchange REVERTED -- 17.4 GB WRITE_SIZE, HBM-BW-bound, 8516 us).
// R11 taught: system-scope relaxed ops are HBM-routed (uncoalesced, ~4x
// write amplification) => R10's 3 serial exchange RTs pay HBM latency too.
// Agent scope: sc-bypass of L1/L2 but served at Infinity Cache (the
// cross-XCD coherence point); RELAXED still emits no cache maintenance
// (R6's wbl2/inv came from ACQ/REL ordering, not scope). One variable vs
// R10. Clean-success signature: FETCH ~90MB / WRITE ~95MB (exchange leaves
// HBM counters) + dur 4.7-5.4ms. Counters-drop-but-dur-flat => latency not
// scope-bound. No-drop => agent also HBM-routed, scope dead end.

#define B_TOTAL   1024
#define H_DIM     256
#define F_WARM    32
#define F_AUTO    24
#define O_DIM     8
#define T_WARM    512
#define T_TOTAL   1024
#define N4H       1024
#define A_STR     168   // x(32)+h(128)+pad(8): 336 B/row, 16B-aligned

typedef __attribute__((ext_vector_type(8))) short short8;
typedef __attribute__((ext_vector_type(4))) float float4v;

#define GLOBAL_AS __attribute__((address_space(1)))
#define LDS_AS    __attribute__((address_space(3)))
#define XSCOPE    __HIP_MEMORY_SCOPE_AGENT

__device__ __forceinline__ short f2bf(float x) {
    union { float f; uint32_t u; } v; v.f = x;
    uint32_t r = v.u + 0x7FFFu + ((v.u >> 16) & 1u);   // RNE
    return (short)(r >> 16);
}
__device__ __forceinline__ float sigmoid_(float x) {
    const float e = __expf(-x);
    return __builtin_amdgcn_rcpf(1.0f + e);
}
__device__ __forceinline__ float tanh_(float x) {
    const float e = __expf(-2.0f * fabsf(x));
    const float t = (1.0f - e) * __builtin_amdgcn_rcpf(1.0f + e);
    return x >= 0.0f ? t : -t;
}

__global__ __launch_bounds__(256, 1)
void lstm_pair(const float* __restrict__ c0, const float* __restrict__ h0,
               const float* __restrict__ warm, const float* __restrict__ autoin,
               const float* __restrict__ W_ih, const float* __restrict__ W_hh,
               const float* __restrict__ bvec, const float* __restrict__ W_out,
               const float* __restrict__ b_out, float* __restrict__ out,
               unsigned short* __restrict__ ws)
{
    const int tid  = threadIdx.x;
    const int w    = tid >> 6;        // wave 0..3 -> own h-units [w*32, +32)
    const int l    = tid & 63;
    const int n16  = l & 15;          // MFMA n / A row (m)
    const int kg   = l >> 4;          // k-group 0..3
    const int bid  = blockIdx.x;
    const int half = bid >> 6;        // N-half: h-units [half*128, +128)
    const int row0 = (bid & 63) * 16; // batch rows
    const int hb   = half * 128;      // own h base (global h index)
    const int qb   = 128 - hb;        // partner h base

    uint32_t* myflag = (uint32_t*)((char*)ws + (size_t)bid * 64);
    uint32_t* pflag  = (uint32_t*)((char*)ws + (size_t)(bid ^ 64) * 64);
    uint32_t* obuf32 = (uint32_t*)((char*)ws + 8192) + (size_t)bid * 2048;
    uint32_t* pbuf32 = (uint32_t*)((char*)ws + 8192) + (size_t)(bid ^ 64) * 2048;

    __shared__ __align__(16) short Abuf[2][16 * A_STR]; // ping-pong A tiles
    __shared__ __align__(16) unsigned short wsWl[4096]; // W_out MFMA B-frags
    __shared__ float biasL[512];                        // own 4 gates x 128
    __shared__ __align__(16) float xstage[512];         // x_{t+1} prefetch

    // ---- W_out frags -> LDS ----
    for (int idx = tid; idx < 4096; idx += 256) {
        const int i = idx & 7, lane = (idx >> 3) & 63, kk = idx >> 9;
        const int k = kk * 32 + (lane >> 4) * 8 + i;
        const int n = lane & 15;
        wsWl[idx] = (unsigned short)((n < O_DIM) ? f2bf(W_out[k * O_DIM + n]) : (short)0);
    }
    // ---- bias: own 512 cols, layout [g][128] ----
    #pragma unroll
    for (int e = 0; e < 2; ++e) {
        const int idx = tid + e * 256;
        const int g = idx >> 7, loc = idx & 127;
        biasL[idx] = bvec[g * 256 + hb + loc];
    }

    // ---- register weights: 72 frags = 288 regs (compile-time indexed) ----
    short8 bwx[4][2];       // x chunk (W_ih rows 0..31)
    short8 bwo[4][4][2];    // own-h chunks c=0..3
    short8 bwp[4][4][2];    // partner-h chunks
    #pragma unroll
    for (int g = 0; g < 4; ++g)
        #pragma unroll
        for (int j = 0; j < 2; ++j) {
            const int col = g * 256 + hb + w * 32 + j * 16 + n16;
            {
                short8 f;
                #pragma unroll
                for (int i = 0; i < 8; ++i)
                    f[i] = f2bf(W_ih[(kg * 8 + i) * N4H + col]);
                bwx[g][j] = f;
            }
            #pragma unroll
            for (int c = 0; c < 4; ++c) {
                short8 f, p;
                #pragma unroll
                for (int i = 0; i < 8; ++i) {
                    const int kr = c * 32 + kg * 8 + i;
                    f[i] = f2bf(W_hh[(hb + kr) * N4H + col]);
                    p[i] = f2bf(W_hh[(qb + kr) * N4H + col]);
                }
                bwo[c][g][j] = f;
                bwp[c][g][j] = p;
            }
        }

    const float bout = (w == 0 && n16 < O_DIM) ? b_out[n16] : 0.0f;

    // ---- c state ----
    float creg[2][4];
    #pragma unroll
    for (int j = 0; j < 2; ++j)
        #pragma unroll
        for (int r = 0; r < 4; ++r)
            creg[j][r] = c0[(size_t)(row0 + kg * 4 + r) * H_DIM
                            + (hb + w * 32 + j * 16 + n16)];

    // ---- initial A (buf 0): x_0 + own h0 ----
    #pragma unroll
    for (int e = 0; e < 2; ++e) {
        const int idx = tid + e * 256;
        const int r = idx >> 5, cx = idx & 31;
        Abuf[0][r * A_STR + cx] =
            f2bf(warm[(size_t)(row0 + r) * (T_WARM * F_WARM) + cx]);   // t=0
    }
    #pragma unroll
    for (int e = 0; e < 8; ++e) {
        const int idx = tid + e * 256;
        const int r = idx >> 7, c = idx & 127;
        Abuf[0][r * A_STR + F_WARM + c] = f2bf(h0[(size_t)(row0 + r) * H_DIM + hb + c]);
    }
    // ---- phf init: partner h0 frags ----
    short8 phf[4];
    #pragma unroll
    for (int c = 0; c < 4; ++c) {
        short8 f;
        #pragma unroll
        for (int i = 0; i < 8; ++i)
            f[i] = f2bf(h0[(size_t)(row0 + n16) * H_DIM + qb + c * 32 + kg * 8 + i]);
        phf[c] = f;
    }

    __syncthreads();                            // prologue LDS published
    float bb[2][4];
    #pragma unroll
    for (int j = 0; j < 2; ++j)
        #pragma unroll
        for (int g = 0; g < 4; ++g)
            bb[j][g] = biasL[g * 128 + w * 32 + j * 16 + n16];

    const int aoff = n16 * A_STR + kg * 8;
    short* curp = &Abuf[0][0];
    short* nxtp = &Abuf[1][0];
    const short8* wsW8 = (const short8*)wsWl;
    const int shx = (n16 & 1) * 16;             // row half in u32 word

    for (int t = 0; t < T_TOTAL; ++t) {
        __syncthreads();                        // A_t: buf[t&1] + publishes drained

        if (tid == 0)                           // h_{t-1} readable (drained at A_t)
            __hip_atomic_store(myflag, (uint32_t)t, __ATOMIC_RELAXED, XSCOPE);

        // ---- async prefetch x_{t+1} -> xstage ----
        const int tn = t + 1;
        if (tn < T_TOTAL) {
            #pragma unroll
            for (int e = 0; e < 2; ++e) {
                const int idx = tid + e * 256;
                const int r = idx >> 5, cx = idx & 31;
                const float* gp;
                if (tn < T_WARM)
                    gp = &warm[(size_t)(row0 + r) * (T_WARM * F_WARM)
                               + (size_t)tn * F_WARM + cx];
                else
                    gp = &autoin[(size_t)(row0 + r) * (T_WARM * F_AUTO)
                                 + (size_t)(tn - T_WARM) * F_AUTO
                                 + ((cx < F_AUTO) ? cx : 0)];
                __builtin_amdgcn_global_load_lds(
                    (const GLOBAL_AS void*)gp,
                    (LDS_AS void*)&xstage[e * 256 + w * 64], 4, 0, 0);
            }
        }

        // ---- own A-frags from current buffer ----
        const short* ab = curp + aoff;
        short8 afh[4];
        #pragma unroll
        for (int c = 0; c < 4; ++c)
            afh[c] = *(const short8*)(ab + 32 + c * 32);

        // ---- own-chunk MFMAs FIRST (no phf dependency; covers poll) ----
        float4v acc[4][2];
        #pragma unroll
        for (int g = 0; g < 4; ++g)
            #pragma unroll
            for (int j = 0; j < 2; ++j)
                acc[g][j] = (float4v){0.f, 0.f, 0.f, 0.f};
        #pragma unroll
        for (int c = 0; c < 4; ++c)
            #pragma unroll
            for (int g = 0; g < 4; ++g)
                #pragma unroll
                for (int j = 0; j < 2; ++j)
                    acc[g][j] = __builtin_amdgcn_mfma_f32_16x16x32_bf16(
                                    afh[c], bwo[c][g][j], acc[g][j], 0, 0, 0);

        // ---- poll partner flag >= t, then phf loads (h_{t-1}) ----
        if (t >= 1) {
            while (__hip_atomic_load(pflag, __ATOMIC_RELAXED, XSCOPE) < (uint32_t)t)
                __builtin_amdgcn_s_sleep(1);
            asm volatile("" ::: "memory");
            const uint32_t* pb = pbuf32 + ((t - 1) & 1) * 1024;
            #pragma unroll
            for (int c = 0; c < 4; ++c) {
                uint32_t wv[8];
                #pragma unroll
                for (int i = 0; i < 8; ++i)
                    wv[i] = __hip_atomic_load(&pb[(c * 32 + kg * 8 + i) * 8 + (n16 >> 1)],
                                              __ATOMIC_RELAXED, XSCOPE);
                short8 f;
                #pragma unroll
                for (int i = 0; i < 8; ++i)
                    f[i] = (short)((wv[i] >> shx) & 0xFFFFu);
                phf[c] = f;
            }
        }

        // ---- partner-chunk MFMAs ----
        #pragma unroll
        for (int c = 0; c < 4; ++c)
            #pragma unroll
            for (int g = 0; g < 4; ++g)
                #pragma unroll
                for (int j = 0; j < 2; ++j)
                    acc[g][j] = __builtin_amdgcn_mfma_f32_16x16x32_bf16(
                                    phf[c], bwp[c][g][j], acc[g][j], 0, 0, 0);

        // ---- wave0: y_{t-1} (skip for half1 during warm: y unused) ----
        if (w == 0 && t >= 1 && (half == 0 || t >= T_WARM)) {
            float4v ya = (float4v){bout, bout, bout, bout};
            #pragma unroll
            for (int c = 0; c < 4; ++c)
                ya = __builtin_amdgcn_mfma_f32_16x16x32_bf16(
                         afh[c], wsW8[(hb / 32 + c) * 64 + l], ya, 0, 0, 0);
            #pragma unroll
            for (int c = 0; c < 4; ++c)
                ya = __builtin_amdgcn_mfma_f32_16x16x32_bf16(
                         phf[c], wsW8[(qb / 32 + c) * 64 + l], ya, 0, 0, 0);
            if (n16 < O_DIM) {
                if (half == 0) {
                    #pragma unroll
                    for (int r = 0; r < 4; ++r)
                        out[(size_t)(row0 + kg * 4 + r) * (T_TOTAL * O_DIM)
                            + (size_t)(t - 1) * O_DIM + n16] = ya[r];
                }
                if (t >= T_WARM) {                      // feedback cols [24,32)
                    #pragma unroll
                    for (int r = 0; r < 4; ++r)
                        curp[(kg * 4 + r) * A_STR + F_AUTO + n16] = f2bf(ya[r]);
                }
            }
        }

        if (t >= T_WARM) __syncthreads();       // B: feedback cols ready

        {
            const short8 af = *(const short8*)(ab);     // x chunk (+feedback)
            #pragma unroll
            for (int g = 0; g < 4; ++g)
                #pragma unroll
                for (int j = 0; j < 2; ++j)
                    acc[g][j] = __builtin_amdgcn_mfma_f32_16x16x32_bf16(
                                    af, bwx[g][j], acc[g][j], 0, 0, 0);
        }

        // ---- gates + c/h update (8 h-vals/thread); HW bf16 pack ----
        uint32_t hp[4];
        #pragma unroll
        for (int j = 0; j < 2; ++j) {
            float hv0, hv1, hv2, hv3;
            #pragma unroll
            for (int r = 0; r < 4; ++r) {
                const float ig = sigmoid_(acc[0][j][r] + bb[j][0]);
                const float fg = sigmoid_(acc[1][j][r] + bb[j][1]);
                const float gg = tanh_(acc[2][j][r] + bb[j][2]);
                const float og = sigmoid_(acc[3][j][r] + bb[j][3]);
                const float cc = fg * creg[j][r] + ig * gg;
                creg[j][r] = cc;
                const float hh = og * tanh_(cc);
                if (r == 0) hv0 = hh; else if (r == 1) hv1 = hh;
                else if (r == 2) hv2 = hh; else hv3 = hh;
            }
            uint32_t u0, u1;
            asm("v_cvt_pk_bf16_f32 %0, %1, %2" : "=v"(u0) : "v"(hv0), "v"(hv1));
            asm("v_cvt_pk_bf16_f32 %0, %1, %2" : "=v"(u1) : "v"(hv2), "v"(hv3));
            hp[j * 2 + 0] = u0;
            hp[j * 2 + 1] = u1;
        }

        // ---- drain x-prefetch loads (issued at step top; cheap) BEFORE
        //      issuing UC publishes, so this only waits the old loads.
        asm volatile("s_waitcnt vmcnt(0)" ::: "memory");

        // ---- commit prefetched x_{t+1} into NEXT buffer ----
        if (tn < T_TOTAL) {
            #pragma unroll
            for (int e = 0; e < 2; ++e) {
                const int idx = tid + e * 256;
                const int r = idx >> 5, cx = idx & 31;
                if (tn < T_WARM || cx < F_AUTO)
                    nxtp[r * A_STR + cx] = f2bf(xstage[idx]);
            }
        }

        // ---- publish h_t: u32 row-pair words, relaxed agent-scope ----
        {
            uint32_t* ob = obuf32 + (t & 1) * 1024;
            #pragma unroll
            for (int j = 0; j < 2; ++j) {
                const int cl = w * 32 + j * 16 + n16;
                __hip_atomic_store(&ob[cl * 8 + kg * 2 + 0], hp[j * 2 + 0],
                                   __ATOMIC_RELAXED, XSCOPE);
                __hip_atomic_store(&ob[cl * 8 + kg * 2 + 1], hp[j * 2 + 1],
                                   __ATOMIC_RELAXED, XSCOPE);
            }
        }

        // ---- write own h_t into NEXT buffer ----
        #pragma unroll
        for (int j = 0; j < 2; ++j) {
            const int ac = F_WARM + w * 32 + j * 16 + n16;
            const uint32_t u0 = hp[j * 2], u1 = hp[j * 2 + 1];
            nxtp[(kg * 4 + 0) * A_STR + ac] = (short)(u0 & 0xFFFF);
            nxtp[(kg * 4 + 1) * A_STR + ac] = (short)(u0 >> 16);
            nxtp[(kg * 4 + 2) * A_STR + ac] = (short)(u1 & 0xFFFF);
            nxtp[(kg * 4 + 3) * A_STR + ac] = (short)(u1 >> 16);
        }

        { short* tswap = curp; curp = nxtp; nxtp = tswap; }
        // loop-top barrier A_{t+1} drains publishes + ds, publishes buf[(t+1)&1]
    }

    // ---- epilogue: y_{T-1} (wave0; needs partner h_{T-1}) ----
    __syncthreads();                            // drains final publishes
    if (tid == 0)
        __hip_atomic_store(myflag, (uint32_t)T_TOTAL, __ATOMIC_RELAXED, XSCOPE);
    if (w == 0) {
        while (__hip_atomic_load(pflag, __ATOMIC_RELAXED, XSCOPE) < (uint32_t)T_TOTAL)
            __builtin_amdgcn_s_sleep(1);
        asm volatile("" ::: "memory");
        const uint32_t* pb = pbuf32 + ((T_TOTAL - 1) & 1) * 1024;
        #pragma unroll
        for (int c = 0; c < 4; ++c) {
            uint32_t wv[8];
            #pragma unroll
            for (int i = 0; i < 8; ++i)
                wv[i] = __hip_atomic_load(&pb[(c * 32 + kg * 8 + i) * 8 + (n16 >> 1)],
                                          __ATOMIC_RELAXED, XSCOPE);
            short8 f;
            #pragma unroll
            for (int i = 0; i < 8; ++i)
                f[i] = (short)((wv[i] >> shx) & 0xFFFFu);
            phf[c] = f;
        }
        const short* ab = curp + aoff;          // curp = buf holding h_{T-1}
        float4v ya = (float4v){bout, bout, bout, bout};
        #pragma unroll
        for (int c = 0; c < 4; ++c)
            ya = __builtin_amdgcn_mfma_f32_16x16x32_bf16(
                     *(const short8*)(ab + 32 + c * 32),
                     wsW8[(hb / 32 + c) * 64 + l], ya, 0, 0, 0);
        #pragma unroll
        for (int c = 0; c < 4; ++c)
            ya = __builtin_amdgcn_mfma_f32_16x16x32_bf16(
                     phf[c], wsW8[(qb / 32 + c) * 64 + l], ya, 0, 0, 0);
        if (half == 0 && n16 < O_DIM) {
            #pragma unroll
            for (int r = 0; r < 4; ++r)
                out[(size_t)(row0 + kg * 4 + r) * (T_TOTAL * O_DIM)
                    + (size_t)(T_TOTAL - 1) * O_DIM + n16] = ya[r];
        }
    }
}

extern "C" void kernel_launch(void* const* d_in, const int* in_sizes, int n_in,
                              void* d_out, int out_size, void* d_ws, size_t ws_size,
                              hipStream_t stream) {
    (void)in_sizes; (void)n_in; (void)out_size; (void)ws_size;
    const float* c0   = (const float*)d_in[0];
    const float* h0   = (const float*)d_in[1];
    const float* warm = (const float*)d_in[2];
    const float* aut  = (const float*)d_in[3];
    const float* Wih  = (const float*)d_in[4];
    const float* Whh  = (const float*)d_in[5];
    const float* b    = (const float*)d_in[6];
    const float* Wout = (const float*)d_in[7];
    const float* bout = (const float*)d_in[8];
    float* out = (float*)d_out;
    unsigned short* ws = (unsigned short*)d_ws;
    // ws layout: [0,8KB) flags (64B/WG); [8KB,8KB+1MB) h-exchange ping-pong.
    hipMemsetAsync(d_ws, 0, 8192, stream);
    hipLaunchKernelGGL(lstm_pair, dim3(128), dim3(256), 0, stream,
                       c0, h0, warm, aut, Wih, Whh, b, Wout, bout, out, ws);
}

// Round 9
// 3636.541 us; speedup vs baseline: 2.3418x; 1.6475x over previous
//
#include <hip/hip_runtime.h>
#include <stdint.h>

// R13: 4-way N-split, 256 WGs on ALL 256 CUs (from R10/R12's 5991 us).
// R12 null => exchange scope irrelevant; latency terms (~9.6k cy/step:
// barrier drain + flag RT + data RT + skew) are decomposition-structural
// and independent of per-WG work (unchanged R5->R10). So: shrink the BUSY
// terms and CU-multiply while holding latency structure constant.
//  - WG = (batch tile 16 rows) x (h-quarter 64 units). 64 tiles x 4 = 256.
//  - exchange with 3 partners, but RT count UNCHANGED: 3 flag loads issue
//    together (1 RT), 3 slice loads issue together (1 RT); published bytes
//    per step constant (2KB x 256 vs 4KB x 128).
//  - weights 144 regs/wave all-register (bwx 16 + bwo 32 + bwhp 96);
//    phf 3x2 frags = 24 regs; partner-relative indexing (no runtime reg idx).
//  - gate VALU halves (4 h-units/thread, j=1).
//  - pre-issued flag loads after barrier A (own MFMAs cover the RT);
//    warm: x-MFMA moved before poll as extra data-RT cover (no feedback dep).
// Decision: 4.8-6.0ms => latency floor structural -> R14 tile-pair
// interleave; >6.0ms => 4-way skew -> revert R12.

#define B_TOTAL   1024
#define H_DIM     256
#define F_WARM    32
#define F_AUTO    24
#define O_DIM     8
#define T_WARM    512
#define T_TOTAL   1024
#define N4H       1024
#define A_STR     104   // x(32)+h(64)+pad(8): 208 B/row, 16B-aligned

typedef __attribute__((ext_vector_type(8))) short short8;
typedef __attribute__((ext_vector_type(4))) float float4v;

#define GLOBAL_AS __attribute__((address_space(1)))
#define LDS_AS    __attribute__((address_space(3)))
#define XSCOPE    __HIP_MEMORY_SCOPE_AGENT

__device__ __forceinline__ short f2bf(float x) {
    union { float f; uint32_t u; } v; v.f = x;
    uint32_t r = v.u + 0x7FFFu + ((v.u >> 16) & 1u);   // RNE
    return (short)(r >> 16);
}
__device__ __forceinline__ float sigmoid_(float x) {
    const float e = __expf(-x);
    return __builtin_amdgcn_rcpf(1.0f + e);
}
__device__ __forceinline__ float tanh_(float x) {
    const float e = __expf(-2.0f * fabsf(x));
    const float t = (1.0f - e) * __builtin_amdgcn_rcpf(1.0f + e);
    return x >= 0.0f ? t : -t;
}
__device__ __forceinline__ uint32_t uc_ld(const uint32_t* p) {
    return __hip_atomic_load(p, __ATOMIC_RELAXED, XSCOPE);
}
__device__ __forceinline__ void uc_st(uint32_t* p, uint32_t v) {
    __hip_atomic_store(p, v, __ATOMIC_RELAXED, XSCOPE);
}

__global__ __launch_bounds__(256, 1)
void lstm_q4(const float* __restrict__ c0, const float* __restrict__ h0,
             const float* __restrict__ warm, const float* __restrict__ autoin,
             const float* __restrict__ W_ih, const float* __restrict__ W_hh,
             const float* __restrict__ bvec, const float* __restrict__ W_out,
             const float* __restrict__ b_out, float* __restrict__ out,
             unsigned short* __restrict__ ws)
{
    const int tid  = threadIdx.x;
    const int w    = tid >> 6;        // wave 0..3 -> own h-units [q*64+w*16,+16)
    const int l    = tid & 63;
    const int n16  = l & 15;          // MFMA n / A row (m)
    const int kg   = l >> 4;          // k-group 0..3
    const int bid  = blockIdx.x;
    const int tile = bid & 63;        // batch tile
    const int q    = bid >> 6;        // h-quarter 0..3
    const int row0 = tile * 16;
    const int hcol = q * 64 + w * 16 + n16;   // own global h col for this thread
    const int cl   = w * 16 + n16;            // own local col (0..63)

    const int pb0 = ((q + 1) & 3) * 64 + tile;
    const int pb1 = ((q + 2) & 3) * 64 + tile;
    const int pb2 = ((q + 3) & 3) * 64 + tile;

    uint32_t* myflag = (uint32_t*)((char*)ws + (size_t)bid * 64);
    const uint32_t* pf0 = (const uint32_t*)((char*)ws + (size_t)pb0 * 64);
    const uint32_t* pf1 = (const uint32_t*)((char*)ws + (size_t)pb1 * 64);
    const uint32_t* pf2 = (const uint32_t*)((char*)ws + (size_t)pb2 * 64);
    uint32_t* xbase = (uint32_t*)((char*)ws + 16384);
    uint32_t*       obuf = xbase + (size_t)bid * 1024;   // 2 parity x 512 u32
    const uint32_t* pd0  = xbase + (size_t)pb0 * 1024;
    const uint32_t* pd1  = xbase + (size_t)pb1 * 1024;
    const uint32_t* pd2  = xbase + (size_t)pb2 * 1024;

    __shared__ __align__(16) short Abuf[2][16 * A_STR]; // [x(32) | own h(64) | pad]
    __shared__ __align__(16) unsigned short wsWl[4096]; // W_out MFMA B-frags (K=256)
    __shared__ float biasL[256];                        // own 4 gates x 64
    __shared__ __align__(16) float xstage[512];         // x_{t+1} prefetch

    // ---- W_out frags -> LDS ----
    for (int idx = tid; idx < 4096; idx += 256) {
        const int i = idx & 7, lane = (idx >> 3) & 63, kk = idx >> 9;
        const int k = kk * 32 + (lane >> 4) * 8 + i;
        const int n = lane & 15;
        wsWl[idx] = (unsigned short)((n < O_DIM) ? f2bf(W_out[k * O_DIM + n]) : (short)0);
    }
    // ---- bias: own 256 cols, layout [g][64] ----
    {
        const int g = tid >> 6, loc = tid & 63;
        biasL[tid] = bvec[g * 256 + q * 64 + loc];
    }

    // ---- register weights: 36 frags = 144 regs (compile-time indexed) ----
    short8 bwx[4];          // x chunk (W_ih rows 0..31), own cols
    short8 bwo[2][4];       // own h chunks lc=0,1 (W_hh rows q*64+lc*32..)
    short8 bwhp[3][2][4];   // partner chunks, partner-relative pi order
    #pragma unroll
    for (int g = 0; g < 4; ++g) {
        const int col = g * 256 + hcol;
        {
            short8 f;
            #pragma unroll
            for (int i = 0; i < 8; ++i)
                f[i] = f2bf(W_ih[(kg * 8 + i) * N4H + col]);
            bwx[g] = f;
        }
        #pragma unroll
        for (int lc = 0; lc < 2; ++lc) {
            short8 f;
            #pragma unroll
            for (int i = 0; i < 8; ++i)
                f[i] = f2bf(W_hh[(q * 64 + lc * 32 + kg * 8 + i) * N4H + col]);
            bwo[lc][g] = f;
        }
        #pragma unroll
        for (int pi = 0; pi < 3; ++pi) {
            const int qq = (q + 1 + pi) & 3;
            #pragma unroll
            for (int lc = 0; lc < 2; ++lc) {
                short8 f;
                #pragma unroll
                for (int i = 0; i < 8; ++i)
                    f[i] = f2bf(W_hh[(qq * 64 + lc * 32 + kg * 8 + i) * N4H + col]);
                bwhp[pi][lc][g] = f;
            }
        }
    }

    const float bout = (w == 0 && n16 < O_DIM) ? b_out[n16] : 0.0f;

    // ---- c state: rows kg*4+r, own col hcol ----
    float creg[4];
    #pragma unroll
    for (int r = 0; r < 4; ++r)
        creg[r] = c0[(size_t)(row0 + kg * 4 + r) * H_DIM + hcol];

    // ---- initial A (buf 0): x_0 + own h0 slice ----
    #pragma unroll
    for (int e = 0; e < 2; ++e) {
        const int idx = tid + e * 256;
        const int r = idx >> 5, cx = idx & 31;
        Abuf[0][r * A_STR + cx] =
            f2bf(warm[(size_t)(row0 + r) * (T_WARM * F_WARM) + cx]);   // t=0
    }
    #pragma unroll
    for (int e = 0; e < 4; ++e) {
        const int idx = tid + e * 256;
        const int r = idx >> 6, c = idx & 63;
        Abuf[0][r * A_STR + F_WARM + c] =
            f2bf(h0[(size_t)(row0 + r) * H_DIM + q * 64 + c]);
    }
    // ---- phf init: partner h0 frags (6 chunks) ----
    short8 phf[3][2];
    #pragma unroll
    for (int pi = 0; pi < 3; ++pi) {
        const int qq = (q + 1 + pi) & 3;
        #pragma unroll
        for (int lc = 0; lc < 2; ++lc) {
            short8 f;
            #pragma unroll
            for (int i = 0; i < 8; ++i)
                f[i] = f2bf(h0[(size_t)(row0 + n16) * H_DIM
                               + qq * 64 + lc * 32 + kg * 8 + i]);
            phf[pi][lc] = f;
        }
    }

    __syncthreads();                            // prologue LDS published
    float bb[4];
    #pragma unroll
    for (int g = 0; g < 4; ++g) bb[g] = biasL[g * 64 + cl];

    const int aoff = n16 * A_STR + kg * 8;
    short* curp = &Abuf[0][0];
    short* nxtp = &Abuf[1][0];
    const short8* wsW8 = (const short8*)wsWl;
    const int shx = (n16 & 1) * 16;             // row half in u32 word

    for (int t = 0; t < T_TOTAL; ++t) {
        __syncthreads();                        // A_t: buf + publish-acks drained

        if (tid == 0)                           // h_{t-1} readable
            uc_st(myflag, (uint32_t)t);

        // ---- pre-issue partner flag loads (covered by own MFMAs) ----
        uint32_t fv0 = 0, fv1 = 0, fv2 = 0;
        if (t >= 1) { fv0 = uc_ld(pf0); fv1 = uc_ld(pf1); fv2 = uc_ld(pf2); }

        // ---- async prefetch x_{t+1} -> xstage ----
        const int tn = t + 1;
        if (tn < T_TOTAL) {
            #pragma unroll
            for (int e = 0; e < 2; ++e) {
                const int idx = tid + e * 256;
                const int r = idx >> 5, cx = idx & 31;
                const float* gp;
                if (tn < T_WARM)
                    gp = &warm[(size_t)(row0 + r) * (T_WARM * F_WARM)
                               + (size_t)tn * F_WARM + cx];
                else
                    gp = &autoin[(size_t)(row0 + r) * (T_WARM * F_AUTO)
                                 + (size_t)(tn - T_WARM) * F_AUTO
                                 + ((cx < F_AUTO) ? cx : 0)];
                __builtin_amdgcn_global_load_lds(
                    (const GLOBAL_AS void*)gp,
                    (LDS_AS void*)&xstage[e * 256 + w * 64], 4, 0, 0);
            }
        }

        // ---- own A-frags + own-chunk MFMAs (8) ----
        const short* ab = curp + aoff;
        short8 afh[2];
        #pragma unroll
        for (int lc = 0; lc < 2; ++lc)
            afh[lc] = *(const short8*)(ab + 32 + lc * 32);

        float4v acc[4];
        #pragma unroll
        for (int g = 0; g < 4; ++g)
            acc[g] = (float4v){0.f, 0.f, 0.f, 0.f};
        #pragma unroll
        for (int lc = 0; lc < 2; ++lc)
            #pragma unroll
            for (int g = 0; g < 4; ++g)
                acc[g] = __builtin_amdgcn_mfma_f32_16x16x32_bf16(
                             afh[lc], bwo[lc][g], acc[g], 0, 0, 0);

        // ---- warm: x-chunk MFMA early (no feedback dep; covers data RT) ----
        if (t < T_WARM) {
            const short8 af = *(const short8*)(ab);
            #pragma unroll
            for (int g = 0; g < 4; ++g)
                acc[g] = __builtin_amdgcn_mfma_f32_16x16x32_bf16(
                             af, bwx[g], acc[g], 0, 0, 0);
        }

        // ---- confirm flags (pre-issued), then load partner slices (1 RT) ----
        if (t >= 1) {
            const uint32_t want = (uint32_t)t;
            while (fv0 < want || fv1 < want || fv2 < want) {
                __builtin_amdgcn_s_sleep(1);
                fv0 = uc_ld(pf0); fv1 = uc_ld(pf1); fv2 = uc_ld(pf2);
            }
            asm volatile("" ::: "memory");
            const int slot = ((t - 1) & 1) * 512;
            #pragma unroll
            for (int pi = 0; pi < 3; ++pi) {
                const uint32_t* pd = (pi == 0) ? pd0 : (pi == 1) ? pd1 : pd2;
                #pragma unroll
                for (int lc = 0; lc < 2; ++lc) {
                    uint32_t wv[8];
                    #pragma unroll
                    for (int i = 0; i < 8; ++i)
                        wv[i] = uc_ld(&pd[slot + (lc * 32 + kg * 8 + i) * 8 + (n16 >> 1)]);
                    short8 f;
                    #pragma unroll
                    for (int i = 0; i < 8; ++i)
                        f[i] = (short)((wv[i] >> shx) & 0xFFFFu);
                    phf[pi][lc] = f;
                }
            }
        }

        // ---- partner-chunk MFMAs (24) ----
        #pragma unroll
        for (int pi = 0; pi < 3; ++pi)
            #pragma unroll
            for (int lc = 0; lc < 2; ++lc)
                #pragma unroll
                for (int g = 0; g < 4; ++g)
                    acc[g] = __builtin_amdgcn_mfma_f32_16x16x32_bf16(
                                 phf[pi][lc], bwhp[pi][lc][g], acc[g], 0, 0, 0);

        // ---- wave0: y_{t-1} (q0 always; all quarters during auto) ----
        if (w == 0 && t >= 1 && (q == 0 || t >= T_WARM)) {
            float4v ya = (float4v){bout, bout, bout, bout};
            #pragma unroll
            for (int lc = 0; lc < 2; ++lc)
                ya = __builtin_amdgcn_mfma_f32_16x16x32_bf16(
                         afh[lc], wsW8[(q * 2 + lc) * 64 + l], ya, 0, 0, 0);
            #pragma unroll
            for (int pi = 0; pi < 3; ++pi) {
                const int qq = (q + 1 + pi) & 3;
                #pragma unroll
                for (int lc = 0; lc < 2; ++lc)
                    ya = __builtin_amdgcn_mfma_f32_16x16x32_bf16(
                             phf[pi][lc], wsW8[(qq * 2 + lc) * 64 + l], ya, 0, 0, 0);
            }
            if (n16 < O_DIM) {
                if (q == 0) {
                    #pragma unroll
                    for (int r = 0; r < 4; ++r)
                        out[(size_t)(row0 + kg * 4 + r) * (T_TOTAL * O_DIM)
                            + (size_t)(t - 1) * O_DIM + n16] = ya[r];
                }
                if (t >= T_WARM) {                      // feedback cols [24,32)
                    #pragma unroll
                    for (int r = 0; r < 4; ++r)
                        curp[(kg * 4 + r) * A_STR + F_AUTO + n16] = f2bf(ya[r]);
                }
            }
        }

        // ---- auto: barrier B then x-chunk MFMA (feedback-carrying) ----
        if (t >= T_WARM) {
            __syncthreads();
            const short8 af = *(const short8*)(ab);
            #pragma unroll
            for (int g = 0; g < 4; ++g)
                acc[g] = __builtin_amdgcn_mfma_f32_16x16x32_bf16(
                             af, bwx[g], acc[g], 0, 0, 0);
        }

        // ---- gates + c/h update (4 h-vals/thread); HW bf16 pack ----
        uint32_t hp[2];
        {
            float hv0, hv1, hv2, hv3;
            #pragma unroll
            for (int r = 0; r < 4; ++r) {
                const float ig = sigmoid_(acc[0][r] + bb[0]);
                const float fg = sigmoid_(acc[1][r] + bb[1]);
                const float gg = tanh_(acc[2][r] + bb[2]);
                const float og = sigmoid_(acc[3][r] + bb[3]);
                const float cc = fg * creg[r] + ig * gg;
                creg[r] = cc;
                const float hh = og * tanh_(cc);
                if (r == 0) hv0 = hh; else if (r == 1) hv1 = hh;
                else if (r == 2) hv2 = hh; else hv3 = hh;
            }
            uint32_t u0, u1;
            asm("v_cvt_pk_bf16_f32 %0, %1, %2" : "=v"(u0) : "v"(hv0), "v"(hv1));
            asm("v_cvt_pk_bf16_f32 %0, %1, %2" : "=v"(u1) : "v"(hv2), "v"(hv3));
            hp[0] = u0; hp[1] = u1;
        }

        // ---- drain x-prefetch loads (cheap) before issuing UC publishes ----
        asm volatile("s_waitcnt vmcnt(0)" ::: "memory");

        // ---- commit prefetched x_{t+1} into NEXT buffer ----
        if (tn < T_TOTAL) {
            #pragma unroll
            for (int e = 0; e < 2; ++e) {
                const int idx = tid + e * 256;
                const int r = idx >> 5, cx = idx & 31;
                if (tn < T_WARM || cx < F_AUTO)
                    nxtp[r * A_STR + cx] = f2bf(xstage[idx]);
            }
        }

        // ---- publish own h_t slice (2 u32/thread) ----
        {
            uint32_t* ob = obuf + (t & 1) * 512;
            uc_st(&ob[cl * 8 + kg * 2 + 0], hp[0]);
            uc_st(&ob[cl * 8 + kg * 2 + 1], hp[1]);
        }

        // ---- write own h_t into NEXT buffer ----
        {
            const int ac = F_WARM + cl;
            nxtp[(kg * 4 + 0) * A_STR + ac] = (short)(hp[0] & 0xFFFF);
            nxtp[(kg * 4 + 1) * A_STR + ac] = (short)(hp[0] >> 16);
            nxtp[(kg * 4 + 2) * A_STR + ac] = (short)(hp[1] & 0xFFFF);
            nxtp[(kg * 4 + 3) * A_STR + ac] = (short)(hp[1] >> 16);
        }

        { short* tswap = curp; curp = nxtp; nxtp = tswap; }
        // loop-top barrier A_{t+1} drains publishes; buf[(t+1)&1] ready
    }

    // ---- epilogue: y_{T-1} (q0 wave0; needs partner h_{T-1}) ----
    __syncthreads();                            // drains final publishes
    if (tid == 0)
        uc_st(myflag, (uint32_t)T_TOTAL);
    if (q == 0 && w == 0) {
        const uint32_t want = (uint32_t)T_TOTAL;
        uint32_t fv0 = uc_ld(pf0), fv1 = uc_ld(pf1), fv2 = uc_ld(pf2);
        while (fv0 < want || fv1 < want || fv2 < want) {
            __builtin_amdgcn_s_sleep(1);
            fv0 = uc_ld(pf0); fv1 = uc_ld(pf1); fv2 = uc_ld(pf2);
        }
        asm volatile("" ::: "memory");
        const int slot = ((T_TOTAL - 1) & 1) * 512;
        #pragma unroll
        for (int pi = 0; pi < 3; ++pi) {
            const uint32_t* pd = (pi == 0) ? pd0 : (pi == 1) ? pd1 : pd2;
            #pragma unroll
            for (int lc = 0; lc < 2; ++lc) {
                uint32_t wv[8];
                #pragma unroll
                for (int i = 0; i < 8; ++i)
                    wv[i] = uc_ld(&pd[slot + (lc * 32 + kg * 8 + i) * 8 + (n16 >> 1)]);
                short8 f;
                #pragma unroll
                for (int i = 0; i < 8; ++i)
                    f[i] = (short)((wv[i] >> shx) & 0xFFFFu);
                phf[pi][lc] = f;
            }
        }
        const short* ab = curp + aoff;          // curp holds h_{T-1}
        float4v ya = (float4v){bout, bout, bout, bout};
        #pragma unroll
        for (int lc = 0; lc < 2; ++lc)
            ya = __builtin_amdgcn_mfma_f32_16x16x32_bf16(
                     *(const short8*)(ab + 32 + lc * 32),
                     wsW8[(0 * 2 + lc) * 64 + l], ya, 0, 0, 0);
        #pragma unroll
        for (int pi = 0; pi < 3; ++pi) {
            const int qq = (0 + 1 + pi) & 3;
            #pragma unroll
            for (int lc = 0; lc < 2; ++lc)
                ya = __builtin_amdgcn_mfma_f32_16x16x32_bf16(
                         phf[pi][lc], wsW8[(qq * 2 + lc) * 64 + l], ya, 0, 0, 0);
        }
        if (n16 < O_DIM) {
            #pragma unroll
            for (int r = 0; r < 4; ++r)
                out[(size_t)(row0 + kg * 4 + r) * (T_TOTAL * O_DIM)
                    + (size_t)(T_TOTAL - 1) * O_DIM + n16] = ya[r];
        }
    }
}

extern "C" void kernel_launch(void* const* d_in, const int* in_sizes, int n_in,
                              void* d_out, int out_size, void* d_ws, size_t ws_size,
                              hipStream_t stream) {
    (void)in_sizes; (void)n_in; (void)out_size; (void)ws_size;
    const float* c0   = (const float*)d_in[0];
    const float* h0   = (const float*)d_in[1];
    const float* warm = (const float*)d_in[2];
    const float* aut  = (const float*)d_in[3];
    const float* Wih  = (const float*)d_in[4];
    const float* Whh  = (const float*)d_in[5];
    const float* b    = (const float*)d_in[6];
    const float* Wout = (const float*)d_in[7];
    const float* bout = (const float*)d_in[8];
    float* out = (float*)d_out;
    unsigned short* ws = (unsigned short*)d_ws;
    // ws layout: [0,16KB) flags (64B/WG); [16KB,16KB+1MB) h-slices:
    //            per WG 2 parity x 2KB (512 u32).
    hipMemsetAsync(d_ws, 0, 16384, stream);
    hipLaunchKernelGGL(lstm_q4, dim3(256), dim3(256), 0, stream,
                       c0, h0, warm, aut, Wih, Whh, b, Wout, bout, out, ws);
}